// Round 4
// baseline (955.042 us; speedup 1.0000x reference)
//
#include <hip/hip_runtime.h>
#include <math.h>

#define PI_F 3.14159265358979323846f

namespace {
constexpr int B_ = 8;
constexpr int L_ = 3072;
constexpr int S_ = 3072;
constexpr int NF = 544;          // fused projection width: 512 + 16 om + 16 th
constexpr int NSC = 8;           // s-chunks for layer-0 attention
constexpr int SCHUNK = S_ / NSC; // 384
}

typedef __attribute__((ext_vector_type(8))) short bf16x8;
typedef __attribute__((ext_vector_type(4))) float f32x4;

__device__ inline f32x4 mfma16(bf16x8 a, bf16x8 b, f32x4 c) {
  return __builtin_amdgcn_mfma_f32_16x16x32_bf16(a, b, c, 0, 0, 0);
}

__device__ inline ushort f2bf(float f) {
  union { float f; unsigned u; } v;
  v.f = f;
  unsigned r = v.u + 0x7FFFu + ((v.u >> 16) & 1u);
  return (ushort)(r >> 16);
}

// async global->LDS, 16B per lane; lds base wave-uniform, dest contiguous.
__device__ inline void gl_lds16(const void* g, void* l) {
  __builtin_amdgcn_global_load_lds(
      (const __attribute__((address_space(1))) unsigned int*)g,
      (__attribute__((address_space(3))) unsigned int*)l, 16, 0, 0);
}

// ---------------------------------------------------------------------------
// packing / casts
// ---------------------------------------------------------------------------
// 4 fused weight sets (layer x {K,Q}) -> BT[set][640][512] bf16 + bias[set][544]
__global__ __launch_bounds__(256)
void pack_fused4(const float* __restrict__ Wq, const float* __restrict__ Wk,
                 const float* __restrict__ Wqo, const float* __restrict__ Wko,
                 const float* __restrict__ Wqt, const float* __restrict__ Wkt,
                 const float* __restrict__ bq, const float* __restrict__ bk,
                 const float* __restrict__ bqo, const float* __restrict__ bko,
                 const float* __restrict__ bqt, const float* __restrict__ bkt,
                 ushort* __restrict__ BTF, float* __restrict__ BF,
                 float* __restrict__ pen) {
  const int set = blockIdx.y;  // 0:L0K 1:L0Q 2:L1K 3:L1Q
  const int layer = set >> 1, qs = set & 1;
  if (blockIdx.x == 0 && set == 0 && threadIdx.x < 16) pen[threadIdx.x] = 0.f;
  const float* Wm = (qs ? Wq : Wk) + layer * 262144;
  const float* Wo_ = (qs ? Wqo : Wko) + layer * 8192;
  const float* Wt = (qs ? Wqt : Wkt) + layer * 8192;
  const float* bm = (qs ? bq : bk) + layer * 512;
  const float* bo_ = (qs ? bqo : bko) + layer * 16;
  const float* bt = (qs ? bqt : bkt) + layer * 16;
  ushort* BT = BTF + (size_t)set * 640 * 512;
  float* bias = BF + set * 544;
  int gid = blockIdx.x * 256 + threadIdx.x;
  if (gid < 640 * 512) {
    int n = gid >> 9, k = gid & 511;
    float v = 0.f;
    if (n < 512) v = Wm[(size_t)k * 512 + n];
    else if (n < 528) v = Wo_[k * 16 + (n - 512)];
    else if (n < 544) v = Wt[k * 16 + (n - 528)];
    BT[gid] = f2bf(v);
  }
  if (gid < 544)
    bias[gid] = (gid < 512) ? bm[gid] : (gid < 528 ? bo_[gid - 512] : bt[gid - 528]);
}

// 4 plain weight sets {V0,V1,O0,O1} -> BT[set][512][512] bf16 + bias[set][512]
__global__ __launch_bounds__(256)
void pack_plain4(const float* __restrict__ Wv, const float* __restrict__ bv,
                 const float* __restrict__ Wo, const float* __restrict__ bo,
                 ushort* __restrict__ BTP, float* __restrict__ BP) {
  const int set = blockIdx.y;  // 0:V0 1:V1 2:O0 3:O1
  const float* W = (set < 2 ? Wv : Wo) + (set & 1) * 262144;
  const float* b = (set < 2 ? bv : bo) + (set & 1) * 512;
  ushort* BT = BTP + (size_t)set * 262144;
  float* bias = BP + set * 512;
  int gid = blockIdx.x * 256 + threadIdx.x;
  if (gid < 512 * 512) {
    int n = gid >> 9, k = gid & 511;
    BT[gid] = f2bf(W[(size_t)k * 512 + n]);
  }
  if (gid < 512) bias[gid] = b[gid];
}

__device__ inline void cast8(const float* src, ushort* dst, int i) {
  float4 a = ((const float4*)src)[(size_t)i * 2];
  float4 b = ((const float4*)src)[(size_t)i * 2 + 1];
  ushort u[8] = {f2bf(a.x), f2bf(a.y), f2bf(a.z), f2bf(a.w),
                 f2bf(b.x), f2bf(b.y), f2bf(b.z), f2bf(b.w)};
  ((uint4*)dst)[i] = *(uint4*)u;
}

// keys/values/I -> bf16
__global__ __launch_bounds__(256)
void cast_all(const float* __restrict__ keys, const float* __restrict__ values,
              const float* __restrict__ I, ushort* __restrict__ keysB,
              ushort* __restrict__ valuesB, ushort* __restrict__ Ib) {
  int gid = blockIdx.x * 256 + threadIdx.x;
  const int big = 24576 * 512 / 8;
  if (gid < big) cast8(keys, keysB, gid);
  else if (gid < 2 * big) cast8(values, valuesB, gid - big);
  else if (gid < 2 * big + 6144) cast8(I, Ib, gid - 2 * big);
}

__global__ __launch_bounds__(256)
void cast_one(const float* __restrict__ src, ushort* __restrict__ dst, int n8) {
  int gid = blockIdx.x * 256 + threadIdx.x;
  if (gid < n8) cast8(src, dst, gid);
}

__global__ void write_pen(const float* __restrict__ pen, float* __restrict__ out) {
  if (threadIdx.x == 0) out[12582912] = pen[0];
  if (threadIdx.x == 1) out[12582913] = pen[1];
}

// ---------------------------------------------------------------------------
// bf16 MFMA GEMM: C[M,Nout] = act(A[M,512] @ BT[Npad,512]^T + bias)
// 128x128 tile, BK=32, 4 waves, global_load_lds 16B staging (m97 structure).
// Row-clamped A staging + masked stores support M not multiple of 128.
// act=1: cols 512..527 relu, 528..543 tanh*pi. outBf=1: store bf16.
// ---------------------------------------------------------------------------
__global__ __launch_bounds__(256)
void gemm_bf16_mfma(const ushort* __restrict__ A, const ushort* __restrict__ BT,
                    const float* __restrict__ bias, void* __restrict__ Cv,
                    int ldc, int M, int Nout, int act, int outBf) {
  __shared__ ushort As[128][32];
  __shared__ ushort Bs[128][32];
  const int tid = threadIdx.x;
  const int wv = tid >> 6, lane = tid & 63, quad = lane >> 4, col = lane & 15;
  const int wm = wv & 1, wn = wv >> 1;
  const int m0 = blockIdx.y * 128, n0 = blockIdx.x * 128;

  const int srow = lane >> 2;
  const int scol = (lane & 3) * 8;
  int ar0 = m0 + wv * 32 + srow;
  int ar1 = ar0 + 16;
  if (ar0 > M - 1) ar0 = M - 1;
  if (ar1 > M - 1) ar1 = M - 1;
  const int br = n0 + wv * 32 + srow;

  f32x4 acc[4][4];
#pragma unroll
  for (int i = 0; i < 4; ++i)
#pragma unroll
    for (int j = 0; j < 4; ++j) {
      f32x4 z = {0.f, 0.f, 0.f, 0.f};
      acc[i][j] = z;
    }

  for (int k0 = 0; k0 < 512; k0 += 32) {
    __syncthreads();
    gl_lds16(A + (size_t)ar0 * 512 + k0 + scol, &As[wv * 32][0]);
    gl_lds16(A + (size_t)ar1 * 512 + k0 + scol, &As[wv * 32 + 16][0]);
    gl_lds16(BT + (size_t)br * 512 + k0 + scol, &Bs[wv * 32][0]);
    gl_lds16(BT + (size_t)(br + 16) * 512 + k0 + scol, &Bs[wv * 32 + 16][0]);
    __syncthreads();
    bf16x8 av[4], bv[4];
#pragma unroll
    for (int mi = 0; mi < 4; ++mi)
      av[mi] = *(const bf16x8*)&As[wm * 64 + mi * 16 + col][quad * 8];
#pragma unroll
    for (int ni = 0; ni < 4; ++ni)
      bv[ni] = *(const bf16x8*)&Bs[wn * 64 + ni * 16 + col][quad * 8];
#pragma unroll
    for (int mi = 0; mi < 4; ++mi)
#pragma unroll
      for (int ni = 0; ni < 4; ++ni)
        acc[mi][ni] = mfma16(av[mi], bv[ni], acc[mi][ni]);
  }

#pragma unroll
  for (int mi = 0; mi < 4; ++mi) {
#pragma unroll
    for (int ni = 0; ni < 4; ++ni) {
      int n = n0 + wn * 64 + ni * 16 + col;
      if (n >= Nout) continue;
      float bs = bias[n];
#pragma unroll
      for (int r = 0; r < 4; ++r) {
        int m = m0 + wm * 64 + mi * 16 + quad * 4 + r;
        if (m >= M) continue;
        float v = acc[mi][ni][r] + bs;
        if (act && n >= 512) v = (n < 528) ? fmaxf(v, 0.f) : tanhf(v) * PI_F;
        if (outBf) ((ushort*)Cv)[(size_t)m * ldc + n] = f2bf(v);
        else ((float*)Cv)[(size_t)m * ldc + n] = v;
      }
    }
  }
}

// ---------------------------------------------------------------------------
// build_qr0: QF0[96][544] -> Qr0bf[h][96][128] bf16, + layer0 q-penalties (x8)
// ---------------------------------------------------------------------------
__global__ __launch_bounds__(256)
void build_qr0(const float* __restrict__ QF0, ushort* __restrict__ Qr0bf,
               float* __restrict__ pen) {
  const int l = blockIdx.x;
  const float* row = QF0 + (size_t)l * NF;
  __shared__ float2 trig[8][2];
  const int tid = threadIdx.x;
  if (tid < 16) {
    int h = tid >> 1, m = tid & 1;
    float om = row[512 + h * 2 + m], th = row[528 + h * 2 + m];
    float qa = fmaf(om, (float)l / 96.f, th);
    trig[h][m] = make_float2(cosf(qa), sinf(qa));
    // penalty
    float thv = th * th;
    float omv = 0.f;
    if (l < 95) {
      float d = QF0[(size_t)(l + 1) * NF + 512 + tid] - row[512 + tid];
      omv = d * d;
    }
#pragma unroll
    for (int off = 1; off < 16; off <<= 1) {
      omv += __shfl_xor(omv, off);
      thv += __shfl_xor(thv, off);
    }
    if (tid == 0) {
      atomicAdd(pen + 0, 8.f * omv);
      atomicAdd(pen + 1, 8.f * thv);
    }
  }
  __syncthreads();
  for (int idx = tid; idx < 1024; idx += 256) {
    int h = idx >> 7, d = idx & 127;
    int m = d >> 6, r = d & 63, c = r >> 4, e = r & 15;
    float qc = row[h * 64 + c * 16 + e];
    float qp = row[h * 64 + (c ^ 1) * 16 + e];
    float2 tg = trig[h][m];
    float sgn = (c == 0 || c == 3) ? -1.f : 1.f;
    Qr0bf[((size_t)h * 96 + l) * 128 + d] = f2bf(fmaf(qc, tg.x, sgn * qp * tg.y));
  }
}

// ---------------------------------------------------------------------------
// build_kr0: KF0[24576][544] -> Kr0bf[(b*8+h)*3072+s][128] bf16, + k-penalties
// grid (48 stile, 8 h, 8 b)
// ---------------------------------------------------------------------------
__global__ __launch_bounds__(256)
void build_kr0(const float* __restrict__ KF0, ushort* __restrict__ Kr0bf,
               float* __restrict__ pen) {
  const int st = blockIdx.x, h = blockIdx.y, b = blockIdx.z;
  const int s0 = st * 64;
  const int tid = threadIdx.x;
  __shared__ float2 trig[64][2];
  if (tid < 128) {
    int s = tid >> 1, m = tid & 1;
    int sg = s0 + s;
    const float* row = KF0 + (size_t)(b * S_ + sg) * NF;
    float om = row[512 + h * 2 + m];
    float th = row[528 + h * 2 + m];
    float ka = fmaf(om, (float)sg * (1.f / (float)S_), th);
    trig[s][m] = make_float2(cosf(ka), sinf(ka));
    float thv = th * th;
    float omv = 0.f;
    if (sg < S_ - 1) {
      float d = KF0[(size_t)(b * S_ + sg + 1) * NF + 512 + h * 2 + m] - om;
      omv = d * d;
    }
#pragma unroll
    for (int off = 1; off < 64; off <<= 1) {
      omv += __shfl_xor(omv, off);
      thv += __shfl_xor(thv, off);
    }
    if ((tid & 63) == 0) {
      atomicAdd(pen + 0, omv);
      atomicAdd(pen + 1, thv);
    }
  }
  __syncthreads();
  ushort* outb = Kr0bf + ((size_t)(b * 8 + h) * S_ + s0) * 128;
  for (int idx = tid; idx < 64 * 128; idx += 256) {
    int s = idx >> 7, d = idx & 127;
    int m = d >> 6, r = d & 63, c = r >> 4, e = r & 15;
    const float* rowh = KF0 + (size_t)(b * S_ + s0 + s) * NF + h * 64;
    float kc = rowh[c * 16 + e];
    float kp = rowh[(c ^ 2) * 16 + e];
    float2 tg = trig[s][m];
    float sgn = (c < 2) ? -1.f : 1.f;
    outb[(size_t)s * 128 + d] = f2bf(fmaf(kc, tg.x, sgn * kp * tg.y));
  }
}

// ---------------------------------------------------------------------------
// build_qr1: QF1[24576][544] -> Qr1bf[(b*8+h)*3072+l][128] bf16, + q1-penalties
// ---------------------------------------------------------------------------
__global__ __launch_bounds__(256)
void build_qr1(const float* __restrict__ QF1, ushort* __restrict__ Qr1bf,
               float* __restrict__ pen) {
  const int st = blockIdx.x, h = blockIdx.y, b = blockIdx.z;
  const int l0 = st * 64;
  const int tid = threadIdx.x;
  __shared__ float2 trig[64][2];
  if (tid < 128) {
    int l = tid >> 1, m = tid & 1;
    int lg = l0 + l;
    const float* row = QF1 + (size_t)(b * L_ + lg) * NF;
    float om = row[512 + h * 2 + m];
    float th = row[528 + h * 2 + m];
    float qa = fmaf(om, (float)lg * (1.f / (float)L_), th);
    trig[l][m] = make_float2(cosf(qa), sinf(qa));
    float thv = th * th;
    float omv = 0.f;
    if (lg < L_ - 1) {
      float d = QF1[(size_t)(b * L_ + lg + 1) * NF + 512 + h * 2 + m] - om;
      omv = d * d;
    }
#pragma unroll
    for (int off = 1; off < 64; off <<= 1) {
      omv += __shfl_xor(omv, off);
      thv += __shfl_xor(thv, off);
    }
    if ((tid & 63) == 0) {
      atomicAdd(pen + 0, omv);
      atomicAdd(pen + 1, thv);
    }
  }
  __syncthreads();
  ushort* outb = Qr1bf + ((size_t)(b * 8 + h) * L_ + l0) * 128;
  for (int idx = tid; idx < 64 * 128; idx += 256) {
    int l = idx >> 7, d = idx & 127;
    int m = d >> 6, r = d & 63, c = r >> 4, e = r & 15;
    const float* rowh = QF1 + (size_t)(b * L_ + l0 + l) * NF + h * 64;
    float qc = rowh[c * 16 + e];
    float qp = rowh[(c ^ 1) * 16 + e];
    float2 tg = trig[l][m];
    float sgn = (c == 0 || c == 3) ? -1.f : 1.f;
    outb[(size_t)l * 128 + d] = f2bf(fmaf(qc, tg.x, sgn * qp * tg.y));
  }
}

// ---------------------------------------------------------------------------
// build_kr1: KF1[768][544] -> Kr1bf[(b*8+h)*96+s][128] bf16, + k1-penalties
// ---------------------------------------------------------------------------
__global__ __launch_bounds__(256)
void build_kr1(const float* __restrict__ KF1, ushort* __restrict__ Kr1bf,
               float* __restrict__ pen) {
  const int rs = blockIdx.x;
  const int b = rs / 96, s = rs % 96;
  const float* row = KF1 + (size_t)rs * NF;
  __shared__ float2 trig[8][2];
  const int tid = threadIdx.x;
  if (tid < 16) {
    int h = tid >> 1, m = tid & 1;
    float om = row[512 + h * 2 + m], th = row[528 + h * 2 + m];
    float ka = fmaf(om, (float)s / 96.f, th);
    trig[h][m] = make_float2(cosf(ka), sinf(ka));
    float thv = th * th;
    float omv = 0.f;
    if (s < 95) {
      float d = KF1[(size_t)(rs + 1) * NF + 512 + tid] - row[512 + tid];
      omv = d * d;
    }
#pragma unroll
    for (int off = 1; off < 16; off <<= 1) {
      omv += __shfl_xor(omv, off);
      thv += __shfl_xor(thv, off);
    }
    if (tid == 0) {
      atomicAdd(pen + 0, omv);
      atomicAdd(pen + 1, thv);
    }
  }
  __syncthreads();
  for (int idx = tid; idx < 1024; idx += 256) {
    int h = idx >> 7, d = idx & 127;
    int m = d >> 6, r = d & 63, c = r >> 4, e = r & 15;
    float kc = row[h * 64 + c * 16 + e];
    float kp = row[h * 64 + (c ^ 2) * 16 + e];
    float2 tg = trig[h][m];
    float sgn = (c < 2) ? -1.f : 1.f;
    Kr1bf[(((size_t)(b * 8 + h)) * 96 + s) * 128 + d] = f2bf(fmaf(kc, tg.x, sgn * kp * tg.y));
  }
}

// build_v1t: V1 fp32 [768][512] -> V1T[(b*8+h)*64+d][96] bf16. grid (8h,8b)
__global__ __launch_bounds__(256)
void build_v1t(const float* __restrict__ V1, ushort* __restrict__ V1T) {
  const int h = blockIdx.x, b = blockIdx.y;
  const int tid = threadIdx.x;
  for (int idx = tid; idx < 6144; idx += 256) {
    int s = idx >> 6, d = idx & 63;
    float v = V1[(size_t)(b * 96 + s) * 512 + h * 64 + d];
    V1T[((size_t)(b * 8 + h) * 64 + d) * 96 + s] = f2bf(v);
  }
}

// ---------------------------------------------------------------------------
// Layer-0 attention. grid (8 sc, 8 h, 8 b). All inputs prebuilt bf16.
// ---------------------------------------------------------------------------
__global__ __launch_bounds__(256)
void attn0_mfma(const ushort* __restrict__ Kr0bf, const ushort* __restrict__ V0bf,
                const ushort* __restrict__ Qr0bf, float* __restrict__ accP,
                float* __restrict__ sumP) {
  const int sc = blockIdx.x, h = blockIdx.y, b = blockIdx.z;
  const int tid = threadIdx.x;
  const int wv = tid >> 6, lane = tid & 63, quad = lane >> 4, col = lane & 15;

  __shared__ __align__(16) ushort Qs[96][136];
  __shared__ __align__(16) ushort Ks[64][136];
  __shared__ __align__(16) ushort Vt[64][72];
  __shared__ __align__(16) ushort Ps[96][72];
  __shared__ float rowsum[96];

  // stage Q once: 96x128 bf16
  {
    const ushort* src = Qr0bf + (size_t)h * 96 * 128;
    for (int idx = tid; idx < 1536; idx += 256) {
      int row = idx >> 4, g = idx & 15;
      uint4 v = *(const uint4*)(src + (size_t)row * 128 + g * 8);
      *(uint4*)&Qs[row][g * 8] = v;
    }
  }
  if (tid < 96) rowsum[tid] = 0.f;

  f32x4 oacc[6];
#pragma unroll
  for (int i = 0; i < 6; ++i) {
    f32x4 z = {0.f, 0.f, 0.f, 0.f};
    oacc[i] = z;
  }

  const int s0g = sc * SCHUNK;
  const ushort* Krb = Kr0bf + (size_t)(b * 8 + h) * S_ * 128;
  for (int t = 0; t < 6; ++t) {
    const int sb = s0g + t * 64;
    __syncthreads();  // prev PV done with Vt/Ps
    for (int idx = tid; idx < 1024; idx += 256) {
      int row = idx >> 4, g = idx & 15;
      uint4 v = *(const uint4*)(Krb + (size_t)(sb + row) * 128 + g * 8);
      *(uint4*)&Ks[row][g * 8] = v;
    }
    for (int idx = tid; idx < 4096; idx += 256) {
      int s = idx >> 6, d = idx & 63;
      Vt[d][s] = V0bf[(size_t)(b * S_ + sb + s) * 512 + h * 64 + d];
    }
    __syncthreads();
    // QK^T: wave wv owns s-cols wv*16..+15
    bf16x8 bk[4];
#pragma unroll
    for (int k = 0; k < 4; ++k)
      bk[k] = *(const bf16x8*)&Ks[wv * 16 + col][k * 32 + quad * 8];
    f32x4 sacc[6];
#pragma unroll
    for (int mt = 0; mt < 6; ++mt) {
      f32x4 z = {0.f, 0.f, 0.f, 0.f};
      sacc[mt] = z;
#pragma unroll
      for (int k = 0; k < 4; ++k) {
        bf16x8 a = *(const bf16x8*)&Qs[mt * 16 + col][k * 32 + quad * 8];
        sacc[mt] = mfma16(a, bk[k], sacc[mt]);
      }
    }
    // exp (tiny logits: max-free), P->LDS, rowsums
#pragma unroll
    for (int mt = 0; mt < 6; ++mt) {
      float pr[4];
#pragma unroll
      for (int r = 0; r < 4; ++r) {
        float p = __expf(sacc[mt][r] * 0.0625f);
        pr[r] = p;
        Ps[mt * 16 + quad * 4 + r][wv * 16 + col] = f2bf(p);
      }
#pragma unroll
      for (int r = 0; r < 4; ++r) {
#pragma unroll
        for (int off = 1; off < 16; off <<= 1) pr[r] += __shfl_xor(pr[r], off);
      }
      if (col == 0) {
#pragma unroll
        for (int r = 0; r < 4; ++r)
          atomicAdd(&rowsum[mt * 16 + quad * 4 + r], pr[r]);
      }
    }
    __syncthreads();
    // PV: wave wv owns d-cols wv*16..+15
    bf16x8 bv0 = *(const bf16x8*)&Vt[wv * 16 + col][quad * 8];
    bf16x8 bv1 = *(const bf16x8*)&Vt[wv * 16 + col][32 + quad * 8];
#pragma unroll
    for (int mt = 0; mt < 6; ++mt) {
      bf16x8 a0 = *(const bf16x8*)&Ps[mt * 16 + col][quad * 8];
      oacc[mt] = mfma16(a0, bv0, oacc[mt]);
      bf16x8 a1 = *(const bf16x8*)&Ps[mt * 16 + col][32 + quad * 8];
      oacc[mt] = mfma16(a1, bv1, oacc[mt]);
    }
  }
  __syncthreads();
  const size_t pbase = (((size_t)(b * 8 + h)) * NSC + sc) * 96;
#pragma unroll
  for (int mt = 0; mt < 6; ++mt) {
#pragma unroll
    for (int r = 0; r < 4; ++r) {
      int l = mt * 16 + quad * 4 + r;
      accP[(pbase + l) * 64 + wv * 16 + col] = oacc[mt][r];
    }
  }
  if (tid < 96) sumP[pbase + tid] = rowsum[tid];
}

// Stage 2: combine chunk partials -> attn0B bf16 [b*96+l][h*64+d]
__global__ __launch_bounds__(256)
void attn0_stage2(const float* __restrict__ accP, const float* __restrict__ sumP,
                  ushort* __restrict__ attn0B) {
  const int l = blockIdx.x, b = blockIdx.y;
  const int tid = threadIdx.x;
  for (int e = tid; e < 512; e += 256) {
    int h = e >> 6, d = e & 63;
    size_t base = ((size_t)(b * 8 + h)) * NSC * 96;
    float num = 0.f, den = 0.f;
    for (int scv = 0; scv < NSC; ++scv) {
      size_t pb = base + (size_t)scv * 96 + l;
      num += accP[pb * 64 + d];
      den += sumP[pb];
    }
    attn0B[((size_t)(b * 96 + l)) * 512 + e] = f2bf(num / den);
  }
}

// ---------------------------------------------------------------------------
// trend_norm -> bf16 output
// ---------------------------------------------------------------------------
__global__ __launch_bounds__(256)
void trend_norm(const float* __restrict__ y, const float* __restrict__ g,
                const float* __restrict__ be, ushort* __restrict__ outp) {
  const int t = blockIdx.x, b = blockIdx.y;
  const int tid = threadIdx.x;
  __shared__ float red[256];
  __shared__ float red2[256];
  float seas[2], trend[2];
  float lsum = 0.f, lsum2 = 0.f;
#pragma unroll
  for (int u = 0; u < 2; ++u) {
    int d = tid + u * 256;
    float tr = 0.f;
    for (int j = -12; j <= 12; ++j) {
      int tt = t + j;
      tt = tt < 0 ? 0 : (tt > 95 ? 95 : tt);
      tr += y[((size_t)(b * 96 + tt)) * 512 + d];
    }
    tr *= (1.f / 25.f);
    float x = y[((size_t)(b * 96 + t)) * 512 + d];
    float se = x - tr;
    seas[u] = se;
    trend[u] = tr;
    lsum += se;
    lsum2 += se * se;
  }
  red[tid] = lsum;
  red2[tid] = lsum2;
  __syncthreads();
  for (int off = 128; off > 0; off >>= 1) {
    if (tid < off) {
      red[tid] += red[tid + off];
      red2[tid] += red2[tid + off];
    }
    __syncthreads();
  }
  float mu = red[0] / 512.f;
  float var = red2[0] / 512.f - mu * mu;
  float rs = rsqrtf(var + 1e-5f);
#pragma unroll
  for (int u = 0; u < 2; ++u) {
    int d = tid + u * 256;
    outp[((size_t)(b * 96 + t)) * 512 + d] =
        f2bf((seas[u] - mu) * rs * g[d] + be[d] + trend[u]);
  }
}

// ---------------------------------------------------------------------------
// Layer-1 attention. grid (12 lgroups of 4x64, 8h, 8b). K/V staged once,
// loop 4 l-tiles. All inputs prebuilt bf16; bf16 output.
// ---------------------------------------------------------------------------
__global__ __launch_bounds__(256)
void attn1_mfma(const ushort* __restrict__ Qr1bf, const ushort* __restrict__ Kr1bf,
                const ushort* __restrict__ V1T, ushort* __restrict__ attn1B) {
  const int lg = blockIdx.x, h = blockIdx.y, b = blockIdx.z;
  const int tid = threadIdx.x;
  const int wv = tid >> 6, lane = tid & 63, quad = lane >> 4, col = lane & 15;

  __shared__ __align__(16) ushort Qs[64][136];
  __shared__ __align__(16) ushort Ks[96][136];
  __shared__ __align__(16) ushort Vt[64][104];
  __shared__ __align__(16) ushort Ps[64][104];

  {
    const ushort* src = Kr1bf + (size_t)(b * 8 + h) * 96 * 128;
    for (int idx = tid; idx < 1536; idx += 256) {
      int row = idx >> 4, g = idx & 15;
      uint4 v = *(const uint4*)(src + (size_t)row * 128 + g * 8);
      *(uint4*)&Ks[row][g * 8] = v;
    }
    const ushort* vsrc = V1T + (size_t)(b * 8 + h) * 64 * 96;
    for (int idx = tid; idx < 768; idx += 256) {
      int row = idx / 12, g = idx % 12;
      uint4 v = *(const uint4*)(vsrc + (size_t)row * 96 + g * 8);
      *(uint4*)&Vt[row][g * 8] = v;
    }
  }
  __syncthreads();

  const ushort* qbase = Qr1bf + (size_t)(b * 8 + h) * L_ * 128;
  for (int lt = 0; lt < 4; ++lt) {
    const int l0 = (lg * 4 + lt) * 64;
    for (int idx = tid; idx < 1024; idx += 256) {
      int row = idx >> 4, g = idx & 15;
      uint4 v = *(const uint4*)(qbase + (size_t)(l0 + row) * 128 + g * 8);
      *(uint4*)&Qs[row][g * 8] = v;
    }
    __syncthreads();
    // QK^T: wave wv owns l-rows wv*16..+15
    bf16x8 aq[4];
#pragma unroll
    for (int k = 0; k < 4; ++k)
      aq[k] = *(const bf16x8*)&Qs[wv * 16 + col][k * 32 + quad * 8];
    f32x4 sacc[6];
#pragma unroll
    for (int nt = 0; nt < 6; ++nt) {
      f32x4 z = {0.f, 0.f, 0.f, 0.f};
      sacc[nt] = z;
#pragma unroll
      for (int k = 0; k < 4; ++k) {
        bf16x8 bkf = *(const bf16x8*)&Ks[nt * 16 + col][k * 32 + quad * 8];
        sacc[nt] = mfma16(aq[k], bkf, sacc[nt]);
      }
    }
    float rsum[4] = {0.f, 0.f, 0.f, 0.f};
#pragma unroll
    for (int nt = 0; nt < 6; ++nt) {
#pragma unroll
      for (int r = 0; r < 4; ++r) {
        float p = __expf(sacc[nt][r] * 0.0625f);
        Ps[wv * 16 + quad * 4 + r][nt * 16 + col] = f2bf(p);
        rsum[r] += p;
      }
    }
#pragma unroll
    for (int r = 0; r < 4; ++r) {
#pragma unroll
      for (int off = 1; off < 16; off <<= 1) rsum[r] += __shfl_xor(rsum[r], off);
    }
    __syncthreads();
    // PV
    bf16x8 ap[3];
#pragma unroll
    for (int kt = 0; kt < 3; ++kt)
      ap[kt] = *(const bf16x8*)&Ps[wv * 16 + col][kt * 32 + quad * 8];
    f32x4 oacc[4];
#pragma unroll
    for (int nt = 0; nt < 4; ++nt) {
      f32x4 z = {0.f, 0.f, 0.f, 0.f};
      oacc[nt] = z;
#pragma unroll
      for (int kt = 0; kt < 3; ++kt) {
        bf16x8 bvf = *(const bf16x8*)&Vt[nt * 16 + col][kt * 32 + quad * 8];
        oacc[nt] = mfma16(ap[kt], bvf, oacc[nt]);
      }
    }
    float inv[4];
#pragma unroll
    for (int r = 0; r < 4; ++r) inv[r] = 1.f / rsum[r];
#pragma unroll
    for (int nt = 0; nt < 4; ++nt) {
#pragma unroll
      for (int r = 0; r < 4; ++r) {
        int l = wv * 16 + quad * 4 + r;
        attn1B[(size_t)(b * L_ + l0 + l) * 512 + h * 64 + nt * 16 + col] =
            f2bf(oacc[nt][r] * inv[r]);
      }
    }
    // next iter re-stages Qs (QK done) ; Ps hazard covered by post-stage sync
  }
}

// ---------------------------------------------------------------------------
extern "C" void kernel_launch(void* const* d_in, const int* in_sizes, int n_in,
                              void* d_out, int out_size, void* d_ws, size_t ws_size,
                              hipStream_t stream) {
  (void)in_sizes; (void)n_in; (void)out_size; (void)ws_size;
  const float* queries = (const float*)d_in[0];
  const float* keys = (const float*)d_in[1];
  const float* values = (const float*)d_in[2];
  const float* Wq = (const float*)d_in[3];
  const float* bq = (const float*)d_in[4];
  const float* Wk = (const float*)d_in[5];
  const float* bk = (const float*)d_in[6];
  const float* Wv = (const float*)d_in[7];
  const float* bv = (const float*)d_in[8];
  const float* Wqo = (const float*)d_in[9];
  const float* bqo = (const float*)d_in[10];
  const float* Wko = (const float*)d_in[11];
  const float* bko = (const float*)d_in[12];
  const float* Wqt = (const float*)d_in[13];
  const float* bqt = (const float*)d_in[14];
  const float* Wkt = (const float*)d_in[15];
  const float* bkt = (const float*)d_in[16];
  const float* Wo = (const float*)d_in[17];
  const float* bo = (const float*)d_in[18];
  const float* I = (const float*)d_in[19];
  const float* ln_g = (const float*)d_in[20];
  const float* ln_b = (const float*)d_in[21];
  float* out = (float*)d_out;

  float* ws = (float*)d_ws;
  size_t off = 0;
  auto alloc = [&](size_t n) {
    float* p = ws + off;
    off += (n + 3) & ~(size_t)3;
    return p;
  };
  auto allocU = [&](size_t n) { return (ushort*)alloc((n + 1) / 2); };

  ushort* BTF = allocU((size_t)4 * 640 * 512);
  float* BF = alloc(4 * 544);
  ushort* BTP = allocU((size_t)4 * 512 * 512);
  float* BP = alloc(4 * 512);
  float* pen = alloc(16);
  ushort* keysB = allocU((size_t)24576 * 512);   // later: small-buffer arena
  ushort* valuesB = allocU((size_t)24576 * 512); // later: queriesB
  ushort* Ib = allocU(96 * 512);
  float* QF0 = alloc(96 * 544);
  ushort* Qr0bf = allocU(8 * 96 * 128);
  float* KF0 = alloc((size_t)24576 * 544);       // later: QF1
  ushort* V0bf = allocU((size_t)24576 * 512);    // later: attn1B
  ushort* Kr0bf = allocU((size_t)64 * 3072 * 128); // later: Qr1bf

  // small-buffer arena inside keysB (dead after the first GEMM)
  float* sb = (float*)keysB;
  size_t soff = 0;
  auto salloc = [&](size_t n) {
    float* p = sb + soff;
    soff += (n + 3) & ~(size_t)3;
    return p;
  };
  float* accP = salloc((size_t)64 * NSC * 96 * 64);
  float* sumP = salloc((size_t)64 * NSC * 96);
  ushort* attn0B = (ushort*)salloc(768 * 512 / 2);
  float* y0 = salloc(768 * 512);
  ushort* xindB = (ushort*)salloc(768 * 512 / 2);
  float* KF1 = salloc(768 * 544);
  float* V1 = salloc(768 * 512);
  ushort* Kr1bf = (ushort*)salloc((size_t)64 * 96 * 128 / 2);
  ushort* V1T = (ushort*)salloc((size_t)64 * 64 * 96 / 2);

  ushort* queriesB = valuesB;
  float* QF1 = KF0;
  ushort* Qr1bf = Kr0bf;
  ushort* attn1B = V0bf;

  ushort* BT0K = BTF;
  ushort* BT0Q = BTF + 327680;
  ushort* BT1K = BTF + 2 * 327680;
  ushort* BT1Q = BTF + 3 * 327680;
  float* B0K = BF;
  float* B0Q = BF + 544;
  float* B1K = BF + 1088;
  float* B1Q = BF + 1632;
  ushort* BTV0 = BTP;
  ushort* BTV1 = BTP + 262144;
  ushort* BTO0 = BTP + 2 * 262144;
  ushort* BTO1 = BTP + 3 * 262144;
  float* BV0 = BP;
  float* BV1 = BP + 512;
  float* BO0 = BP + 1024;
  float* BO1 = BP + 1536;

  pack_fused4<<<dim3(1280, 4), 256, 0, stream>>>(Wq, Wk, Wqo, Wko, Wqt, Wkt, bq, bk,
                                                 bqo, bko, bqt, bkt, BTF, BF, pen);
  pack_plain4<<<dim3(1024, 4), 256, 0, stream>>>(Wv, bv, Wo, bo, BTP, BP);
  cast_all<<<(2 * 1572864 + 6144 + 255) / 256, 256, 0, stream>>>(keys, values, I,
                                                                 keysB, valuesB, Ib);

  // ---- layer 0 ----
  gemm_bf16_mfma<<<dim3(5, 192), 256, 0, stream>>>(keysB, BT0K, B0K, KF0, 544,
                                                   24576, 544, 1, 0);
  gemm_bf16_mfma<<<dim3(4, 192), 256, 0, stream>>>(valuesB, BTV0, BV0, V0bf, 512,
                                                   24576, 512, 0, 1);
  gemm_bf16_mfma<<<dim3(5, 1), 256, 0, stream>>>(Ib, BT0Q, B0Q, QF0, 544,
                                                 96, 544, 1, 0);
  build_qr0<<<96, 256, 0, stream>>>(QF0, Qr0bf, pen);
  build_kr0<<<dim3(48, 8, 8), 256, 0, stream>>>(KF0, Kr0bf, pen);
  attn0_mfma<<<dim3(8, 8, 8), 256, 0, stream>>>(Kr0bf, V0bf, Qr0bf, accP, sumP);
  attn0_stage2<<<dim3(96, 8), 256, 0, stream>>>(accP, sumP, attn0B);
  gemm_bf16_mfma<<<dim3(4, 6), 256, 0, stream>>>(attn0B, BTO0, BO0, y0, 512,
                                                 768, 512, 0, 0);
  trend_norm<<<dim3(96, 8), 256, 0, stream>>>(y0, ln_g, ln_b, xindB);

  // ---- layer 1 ----
  gemm_bf16_mfma<<<dim3(5, 6), 256, 0, stream>>>(xindB, BT1K, B1K, KF1, 544,
                                                 768, 544, 1, 0);
  gemm_bf16_mfma<<<dim3(4, 6), 256, 0, stream>>>(xindB, BTV1, BV1, V1, 512,
                                                 768, 512, 0, 0);
  build_kr1<<<768, 256, 0, stream>>>(KF1, Kr1bf, pen);
  build_v1t<<<dim3(8, 8), 256, 0, stream>>>(V1, V1T);
  cast_one<<<6144, 256, 0, stream>>>(queries, queriesB, 1572864);
  gemm_bf16_mfma<<<dim3(5, 192), 256, 0, stream>>>(queriesB, BT1Q, B1Q, QF1, 544,
                                                   24576, 544, 1, 0);
  build_qr1<<<dim3(48, 8, 8), 256, 0, stream>>>(QF1, Qr1bf, pen);
  attn1_mfma<<<dim3(12, 8, 8), 256, 0, stream>>>(Qr1bf, Kr1bf, V1T, attn1B);
  gemm_bf16_mfma<<<dim3(4, 192), 256, 0, stream>>>(attn1B, BTO1, BO1, out, 512,
                                                   24576, 512, 0, 0);
  write_pen<<<1, 64, 0, stream>>>(pen, out);
}